// Round 1
// baseline (272.282 us; speedup 1.0000x reference)
//
#include <hip/hip_runtime.h>

// ROIAlign (tf.image.crop_and_resize, bilinear, extrapolation_value=0)
// features: [B=4, H=256, W=256, C=64] f32
// rois:     [B=4, N=64, 4] f32  (x1,y1,x2,y2) in image coords (/1024 normalized)
// out:      [B=4, N=64, 56, 56, C=64] f32
//
// Layout: 16 lanes per spatial position (4 channels each, float4);
// each thread processes TWO positions sharing j (rows i, i+1) -> shared
// x-coordinate math, 8 independent 16B loads in flight per thread.
// Output stores are non-temporal: the 205 MB write stream bypasses L2 so
// feature lines stay resident for re-reads.
//
// R1 change: XCD-clustered block swizzle. Grid = 25088 = 8 XCDs x 3136.
// Hardware round-robins blockIdx.x % 8 across XCDs; we invert that so all
// 98 blocks of one roi land consecutively on ONE XCD. Each roi's ~2 MB
// feature footprint is then fetched into exactly one L2 (once), and the
// concurrent per-XCD working set (~2-3 rois) fits the 4 MiB L2 -> the 4x
// bilinear gather amplification is absorbed by L2 instead of LLC.

#define CROP 56
#define FH 256
#define FW 256
#define FC 64

typedef float f32x4 __attribute__((ext_vector_type(4)));

__device__ __forceinline__ f32x4 lerp2d(f32x4 v00, f32x4 v01, f32x4 v10, f32x4 v11,
                                        float lx, float ly) {
    f32x4 top = v00 + (v01 - v00) * lx;
    f32x4 bot = v10 + (v11 - v10) * lx;
    return top + (bot - top) * ly;
}

__global__ __launch_bounds__(256) void roialign_kernel(
    const float* __restrict__ feats,
    const float* __restrict__ rois,
    float* __restrict__ out)
{
    // ---- XCD-clustered swizzle ------------------------------------------
    // blocks per roi: 1568 pairs * 16 lanes / 256 = 98
    // slots per XCD:  25088 / 8 = 3136 = 32 rois * 98 blocks
    const int bid   = blockIdx.x;
    const int xcd   = bid & 7;
    const int slot  = bid >> 3;
    const int roiL  = slot / 98;            // 0..31 (magic-mul)
    const int rblk  = slot - roiL * 98;     // 0..97
    const int rIdx  = (xcd << 5) + roiL;    // 0..255  (= b*64 + n)

    // pair index within this roi: 0..1567
    const int pair  = rblk * 16 + (threadIdx.x >> 4);
    const int c     = (threadIdx.x & 15) << 2;   // channel offset (float4 chunk)
    const int j     = pair % CROP;
    const int ih    = pair / CROP;          // 0..27
    const int i0    = ih * 2;
    const int b     = rIdx >> 6;

    const f32x4 roi = *reinterpret_cast<const f32x4*>(rois + rIdx * 4);
    const float inv_img = 1.0f / 1024.0f;
    const float x1 = roi.x * inv_img;
    const float y1 = roi.y * inv_img;
    const float x2 = roi.z * inv_img;
    const float y2 = roi.w * inv_img;

    const float hm1 = (float)(FH - 1);            // 255
    const float wm1 = (float)(FW - 1);            // 255
    const float inv_cm1 = 1.0f / (float)(CROP - 1);

    // x math shared by both positions
    const float xs = x1 * wm1 + (float)j * (x2 - x1) * wm1 * inv_cm1;
    const bool xvalid = (xs >= 0.0f) && (xs <= wm1);
    const float x0f = floorf(xs);
    const float lx = xs - x0f;
    const int x0  = min(max((int)x0f, 0), FW - 1);
    const int x1i = min(x0 + 1, FW - 1);

    // y math per position
    const float ysA = y1 * hm1 + (float)i0 * (y2 - y1) * hm1 * inv_cm1;
    const float ysB = y1 * hm1 + (float)(i0 + 1) * (y2 - y1) * hm1 * inv_cm1;
    const bool validA = xvalid && (ysA >= 0.0f) && (ysA <= hm1);
    const bool validB = xvalid && (ysB >= 0.0f) && (ysB <= hm1);

    const float y0fA = floorf(ysA);
    const float y0fB = floorf(ysB);
    const float lyA = ysA - y0fA;
    const float lyB = ysB - y0fB;
    const int y0A  = min(max((int)y0fA, 0), FH - 1);
    const int y1A  = min(y0A + 1, FH - 1);
    const int y0B  = min(max((int)y0fB, 0), FH - 1);
    const int y1B  = min(y0B + 1, FH - 1);

    const float* base = feats + (size_t)b * (FH * FW * FC) + c;

    // Issue all 8 loads up front for maximum memory-level parallelism.
    const f32x4 a00 = *reinterpret_cast<const f32x4*>(base + (size_t)(y0A * FW + x0 ) * FC);
    const f32x4 a01 = *reinterpret_cast<const f32x4*>(base + (size_t)(y0A * FW + x1i) * FC);
    const f32x4 a10 = *reinterpret_cast<const f32x4*>(base + (size_t)(y1A * FW + x0 ) * FC);
    const f32x4 a11 = *reinterpret_cast<const f32x4*>(base + (size_t)(y1A * FW + x1i) * FC);
    const f32x4 b00 = *reinterpret_cast<const f32x4*>(base + (size_t)(y0B * FW + x0 ) * FC);
    const f32x4 b01 = *reinterpret_cast<const f32x4*>(base + (size_t)(y0B * FW + x1i) * FC);
    const f32x4 b10 = *reinterpret_cast<const f32x4*>(base + (size_t)(y1B * FW + x0 ) * FC);
    const f32x4 b11 = *reinterpret_cast<const f32x4*>(base + (size_t)(y1B * FW + x1i) * FC);

    f32x4 rA = lerp2d(a00, a01, a10, a11, lx, lyA);
    f32x4 rB = lerp2d(b00, b01, b10, b11, lx, lyB);
    if (!validA) { rA = (f32x4)(0.0f); }
    if (!validB) { rB = (f32x4)(0.0f); }

    // out position indices
    const size_t posA = (size_t)rIdx * (CROP * CROP) + (size_t)i0 * CROP + j;
    float* outA = out + posA * FC + c;
    __builtin_nontemporal_store(rA, reinterpret_cast<f32x4*>(outA));
    __builtin_nontemporal_store(rB, reinterpret_cast<f32x4*>(outA + (size_t)CROP * FC));
}

extern "C" void kernel_launch(void* const* d_in, const int* in_sizes, int n_in,
                              void* d_out, int out_size, void* d_ws, size_t ws_size,
                              hipStream_t stream) {
    const float* feats = (const float*)d_in[0];
    const float* rois  = (const float*)d_in[1];
    float* out = (float*)d_out;

    const int total_pairs = 4 * 64 * CROP * (CROP / 2);   // 401408
    const int total_threads = total_pairs * 16;           // 6422528
    const int block = 256;
    const int grid = total_threads / block;               // 25088 = 8 * 3136 (exact)

    roialign_kernel<<<grid, block, 0, stream>>>(feats, rois, out);
}

// Round 2
// 270.507 us; speedup vs baseline: 1.0066x; 1.0066x over previous
//
#include <hip/hip_runtime.h>

// ROIAlign (tf.image.crop_and_resize, bilinear, extrapolation_value=0)
// features: [B=4, H=256, W=256, C=64] f32
// rois:     [B=4, N=64, 4] f32  (x1,y1,x2,y2) in image coords (/1024 normalized)
// out:      [B=4, N=64, 56, 56, C=64] f32
//
// R2: 4-row thread coarsening.
//  - 16 lanes per spatial position (4 channels each, float4); each thread
//    now computes FOUR output rows (i0..i0+3) at one j: the roi fetch,
//    j/t decode and the whole x-pipeline (xs/floor/clamp/lx) are shared
//    by all 4 rows -> non-lerp VALU per output halves vs the 2-row kernel.
//  - 16 independent 16B loads issued upfront (MLP per wave doubles; at
//    ~3-4 waves/SIMD the per-SIMD outstanding-load count stays ~48-64).
//  - roi load forced scalar via readfirstlane (rIdx is wave-uniform:
//    784 positions/roi = multiple of 4 positions/wave) -> s_load, fewer
//    VGPRs, no per-thread vector roi load.
//  - XCD swizzle from R1 dropped: measured neutral.
//  - NT stores kept: 205 MB write stream bypasses L2.

#define CROP 56
#define FH 256
#define FW 256
#define FC 64

typedef float f32x4 __attribute__((ext_vector_type(4)));

__device__ __forceinline__ f32x4 lerp2d(f32x4 v00, f32x4 v01, f32x4 v10, f32x4 v11,
                                        float lx, float ly) {
    f32x4 top = v00 + (v01 - v00) * lx;
    f32x4 bot = v10 + (v11 - v10) * lx;
    return top + (bot - top) * ly;
}

__global__ __launch_bounds__(256) void roialign_kernel(
    const float* __restrict__ feats,
    const float* __restrict__ rois,
    float* __restrict__ out)
{
    const int g = blockIdx.x * 256 + threadIdx.x;

    const int c = (g & 15) << 2;          // channel offset (float4 chunk)
    const int p = g >> 4;                 // position-group index (j, 4-row group)
    const int j  = p % CROP;
    const int t  = p / CROP;
    const int ih = t % (CROP / 4);        // 0..13
    const int rIdx0 = t / (CROP / 4);     // b*64 + n
    const int i0 = ih * 4;

    // rIdx is wave-uniform (784 positions per roi, 4 positions per wave).
    const int rIdx = __builtin_amdgcn_readfirstlane(rIdx0);
    const int b = rIdx >> 6;

    const f32x4 roi = *reinterpret_cast<const f32x4*>(rois + rIdx * 4);
    const float inv_img = 1.0f / 1024.0f;
    const float x1 = roi.x * inv_img;
    const float y1 = roi.y * inv_img;
    const float x2 = roi.z * inv_img;
    const float y2 = roi.w * inv_img;

    const float hm1 = (float)(FH - 1);            // 255
    const float wm1 = (float)(FW - 1);            // 255
    const float inv_cm1 = 1.0f / (float)(CROP - 1);

    // ---- x math: shared by all 4 rows -----------------------------------
    const float xs = fmaf((float)j, (x2 - x1) * wm1 * inv_cm1, x1 * wm1);
    const bool xvalid = (xs >= 0.0f) && (xs <= wm1);
    const float x0f = floorf(xs);
    const float lx = xs - x0f;
    const int x0  = min(max((int)x0f, 0), FW - 1);
    const int x1i = min(x0 + 1, FW - 1);
    const int xb0 = x0  * FC + c;                 // float-index within a feature row
    const int xb1 = x1i * FC + c;

    // ---- y math per row -------------------------------------------------
    const float ybase = y1 * hm1;
    const float ystep = (y2 - y1) * hm1 * inv_cm1;

    float ly[4];
    int   yb0[4], yb1[4];
    bool  valid[4];
#pragma unroll
    for (int r = 0; r < 4; ++r) {
        const float ys = fmaf((float)(i0 + r), ystep, ybase);
        valid[r] = xvalid && (ys >= 0.0f) && (ys <= hm1);
        const float y0f = floorf(ys);
        ly[r] = ys - y0f;
        const int y0 = min(max((int)y0f, 0), FH - 1);
        const int y1c = min(y0 + 1, FH - 1);
        yb0[r] = y0  * (FW * FC);
        yb1[r] = y1c * (FW * FC);
    }

    const float* base = feats + (size_t)b * (FH * FW * FC);

    // ---- issue all 16 loads upfront for maximum MLP ---------------------
    f32x4 v00[4], v01[4], v10[4], v11[4];
#pragma unroll
    for (int r = 0; r < 4; ++r) {
        v00[r] = *reinterpret_cast<const f32x4*>(base + yb0[r] + xb0);
        v01[r] = *reinterpret_cast<const f32x4*>(base + yb0[r] + xb1);
        v10[r] = *reinterpret_cast<const f32x4*>(base + yb1[r] + xb0);
        v11[r] = *reinterpret_cast<const f32x4*>(base + yb1[r] + xb1);
    }

    // ---- lerp + NT store per row ----------------------------------------
    const size_t pos0 = (size_t)rIdx * (CROP * CROP) + (size_t)i0 * CROP + j;
    float* outp = out + pos0 * FC + c;

#pragma unroll
    for (int r = 0; r < 4; ++r) {
        f32x4 res = lerp2d(v00[r], v01[r], v10[r], v11[r], lx, ly[r]);
        if (!valid[r]) { res = (f32x4)(0.0f); }
        __builtin_nontemporal_store(res,
            reinterpret_cast<f32x4*>(outp + (size_t)r * (CROP * FC)));
    }
}

extern "C" void kernel_launch(void* const* d_in, const int* in_sizes, int n_in,
                              void* d_out, int out_size, void* d_ws, size_t ws_size,
                              hipStream_t stream) {
    const float* feats = (const float*)d_in[0];
    const float* rois  = (const float*)d_in[1];
    float* out = (float*)d_out;

    const int total_groups = 4 * 64 * CROP * (CROP / 4);  // 200704 (j, 4-row groups)
    const int total_threads = total_groups * 16;          // 3211264
    const int block = 256;
    const int grid = total_threads / block;               // 12544 (exact)

    roialign_kernel<<<grid, block, 0, stream>>>(feats, rois, out);
}